// Round 7
// baseline (661.810 us; speedup 1.0000x reference)
//
#include <hip/hip_runtime.h>

#define N_NODES 100000
#define N_EDGES 1600000
#define D 128
#define N_GRAPHS 64
#define BN_EPS 1e-5f
#define NSLICE 16

// dst-buckets for the two-phase scatter
#define BNODES 256
#define NBUCK ((N_NODES + BNODES - 1) / BNODES)  // 391
#define EPB 8192
#define NABLK ((N_EDGES + EPB - 1) / EPB)        // 196

typedef short short8 __attribute__((ext_vector_type(8)));
typedef float f32x4 __attribute__((ext_vector_type(4)));

__device__ inline unsigned short f2bf(float f) {
  unsigned int u = __float_as_uint(f);
  u += 0x7fffu + ((u >> 16) & 1);
  return (unsigned short)(u >> 16);
}
__device__ inline float bf2f(unsigned short h) {
  return __uint_as_float(((unsigned int)h) << 16);
}
__device__ inline void unpack8(uint4 u, float* f) {
  f[0] = __uint_as_float(u.x << 16); f[1] = __uint_as_float(u.x & 0xffff0000u);
  f[2] = __uint_as_float(u.y << 16); f[3] = __uint_as_float(u.y & 0xffff0000u);
  f[4] = __uint_as_float(u.z << 16); f[5] = __uint_as_float(u.z & 0xffff0000u);
  f[6] = __uint_as_float(u.w << 16); f[7] = __uint_as_float(u.w & 0xffff0000u);
}
__device__ inline uint4 pack8(const float* f) {
  uint4 u;
  u.x = f2bf(f[0]) | ((unsigned)f2bf(f[1]) << 16);
  u.y = f2bf(f[2]) | ((unsigned)f2bf(f[3]) << 16);
  u.z = f2bf(f[4]) | ((unsigned)f2bf(f[5]) << 16);
  u.w = f2bf(f[6]) | ((unsigned)f2bf(f[7]) << 16);
  return u;
}

// ---------------- input casts / weight prep ----------------
__global__ __launch_bounds__(256) void k_cast(const float* __restrict__ in,
                                              unsigned short* __restrict__ o) {
  long i = ((long)blockIdx.x * blockDim.x + threadIdx.x) * 8;
  if (i >= (long)N_NODES * D) return;
  float4 a = *(const float4*)(in + i);
  float4 b = *(const float4*)(in + i + 4);
  float f[8] = {a.x, a.y, a.z, a.w, b.x, b.y, b.z, b.w};
  *(uint4*)(o + i) = pack8(f);
}

// Wt[mat][n][k] = bf16(W[mat][k][n]); mat = layer*2 + (0:W1,1:W2)
__global__ __launch_bounds__(128) void k_wprep(const float* __restrict__ W1,
                                               const float* __restrict__ W2,
                                               unsigned short* __restrict__ Wt) {
  int m = blockIdx.x;
  int n = blockIdx.y;
  int k = threadIdx.x;
  int l = m >> 1, s = m & 1;
  const float* W = (s == 0 ? W1 : W2) + (size_t)l * D * D;
  Wt[((size_t)m * D + n) * D + k] = f2bf(W[(size_t)k * D + n]);
}

// ---------------- bucket histogram + scan ----------------
__global__ __launch_bounds__(256) void k_histb(const int* __restrict__ dst,
                                               int* __restrict__ ecount) {
  __shared__ int lh[NBUCK];
  const int t = threadIdx.x;
  const int e0 = blockIdx.x * EPB;
  const int e1 = min(e0 + EPB, N_EDGES);
  for (int i = t; i < NBUCK; i += 256) lh[i] = 0;
  __syncthreads();
  for (int e = e0 + t; e < e1; e += 256) atomicAdd(&lh[dst[e] >> 8], 1);
  __syncthreads();
  for (int i = t; i < NBUCK; i += 256)
    if (lh[i]) atomicAdd(&ecount[i], lh[i]);
}

__global__ __launch_bounds__(512) void k_scanb(const int* __restrict__ ecount,
                                               int* __restrict__ ebase,
                                               int* __restrict__ gcur) {
  __shared__ int ls[512];
  int t = threadIdx.x;
  int v = (t < NBUCK) ? ecount[t] : 0;
  ls[t] = v;
  __syncthreads();
  for (int o = 1; o < 512; o <<= 1) {
    int u = (t >= o) ? ls[t - o] : 0;
    __syncthreads();
    ls[t] += u;
    __syncthreads();
  }
  int ex = ls[t] - v;
  if (t < NBUCK) { ebase[t] = ex; gcur[t] = ex; }
  if (t == 0) ebase[NBUCK] = N_EDGES;
}

// ---------------- two-phase bucketed edge scatter ----------------
__global__ __launch_bounds__(256) void k_scatA(const int* __restrict__ ei,
                                               int* __restrict__ gcur,
                                               int2* __restrict__ pairs) {
  __shared__ int lh[NBUCK];
  __shared__ int lbase[NBUCK];
  const int t = threadIdx.x;
  const int e0 = blockIdx.x * EPB;
  const int e1 = min(e0 + EPB, N_EDGES);
  for (int i = t; i < NBUCK; i += 256) lh[i] = 0;
  __syncthreads();
  for (int e = e0 + t; e < e1; e += 256) atomicAdd(&lh[ei[N_EDGES + e] >> 8], 1);
  __syncthreads();
  for (int i = t; i < NBUCK; i += 256)
    lbase[i] = (lh[i] > 0) ? atomicAdd(&gcur[i], lh[i]) : 0;
  __syncthreads();
  for (int e = e0 + t; e < e1; e += 256) {
    int s = ei[e];
    int d = ei[N_EDGES + e];
    int p = atomicAdd(&lbase[d >> 8], 1);
    pairs[p] = make_int2(s, d);
  }
}

// Phase B: per bucket, build per-node CSR offsets in LDS and place srcs.
__global__ __launch_bounds__(256) void k_scatB(const int2* __restrict__ pairs,
                                               const int* __restrict__ ebase,
                                               int* __restrict__ off,
                                               int* __restrict__ esrc) {
  __shared__ int lcnt[BNODES];
  __shared__ int ls[256];
  const int t = threadIdx.x;
  const int b = blockIdx.x;
  const int nb0 = b * BNODES;
  const int nn = min(BNODES, N_NODES - nb0);
  const int s0 = ebase[b], s1 = ebase[b + 1];
  if (t < nn) lcnt[t] = 0;
  __syncthreads();
  for (int e = s0 + t; e < s1; e += 256) atomicAdd(&lcnt[pairs[e].y - nb0], 1);
  __syncthreads();
  int c0 = (t < nn) ? lcnt[t] : 0;
  ls[t] = c0;
  __syncthreads();
  for (int o = 1; o < 256; o <<= 1) {
    int u = (t >= o) ? ls[t - o] : 0;
    __syncthreads();
    ls[t] += u;
    __syncthreads();
  }
  int pre = ls[t] - c0;  // exclusive prefix within bucket
  if (t < nn) {
    off[nb0 + t] = s0 + pre;
    lcnt[t] = s0 + pre;  // reuse as cursor
  }
  __syncthreads();
  for (int e = s0 + t; e < s1; e += 256) {
    int2 p = pairs[e];
    int pos = atomicAdd(&lcnt[p.y - nb0], 1);
    esrc[pos] = p.x;
  }
  if (b == 0 && t == 0) off[N_NODES] = N_EDGES;
}

// ---------------- agg + (1+eps)*h: one wave per node, uint4/lane ------------
// lane = edge-slot(2b) x feature-lane(4b); 4 edges per iteration, no
// divergence; butterfly shfl_xor folds the 4 slots at the end.
__global__ __launch_bounds__(256) void k_aggz(const unsigned short* __restrict__ h,
                                              const int* __restrict__ off,
                                              const int* __restrict__ esrc,
                                              const float* __restrict__ epsp,
                                              unsigned short* __restrict__ z) {
  const int lane = threadIdx.x & 63;
  const int n = blockIdx.x * 4 + (threadIdx.x >> 6);
  const int es = lane >> 4;   // edge slot 0..3
  const int fl = lane & 15;   // feature lane
  const int c = fl << 3;      // 8 bf16 per lane
  const float e = 1.0f + epsp[0];
  const int o0 = off[n], o1 = off[n + 1];

  float acc[8];
#pragma unroll
  for (int q = 0; q < 8; q++) acc[q] = 0.f;

  int j = o0;
  for (; j + 4 <= o1; j += 4) {
    int s = esrc[j + es];
    uint4 u = *(const uint4*)(h + (size_t)s * D + c);
    float f[8];
    unpack8(u, f);
#pragma unroll
    for (int q = 0; q < 8; q++) acc[q] += f[q];
  }
  if (es < o1 - j) {
    int s = esrc[j + es];
    uint4 u = *(const uint4*)(h + (size_t)s * D + c);
    float f[8];
    unpack8(u, f);
#pragma unroll
    for (int q = 0; q < 8; q++) acc[q] += f[q];
  }
  // fold edge slots (lanes differing in bits 4,5)
#pragma unroll
  for (int q = 0; q < 8; q++) {
    acc[q] += __shfl_xor(acc[q], 16, 64);
    acc[q] += __shfl_xor(acc[q], 32, 64);
  }
  // self contribution
  {
    uint4 u = *(const uint4*)(h + (size_t)n * D + c);
    float f[8];
    unpack8(u, f);
#pragma unroll
    for (int q = 0; q < 8; q++) acc[q] = fmaf(e, f[q], acc[q]);
  }
  if (es == 0) *(uint4*)(z + (size_t)n * D + c) = pack8(acc);
}

// ---------------- elementwise relu(y*sc+tb), bf16 -> bf16 -------------------
__global__ __launch_bounds__(256) void k_ew(const unsigned short* __restrict__ y,
                                            const float* __restrict__ sc,
                                            const float* __restrict__ tb,
                                            unsigned short* __restrict__ o) {
  long i = ((long)blockIdx.x * 256 + threadIdx.x) * 8;
  if (i >= (long)N_NODES * D) return;
  int cb = (int)(i & 127);
  uint4 u = *(const uint4*)(y + i);
  float f[8];
  unpack8(u, f);
#pragma unroll
  for (int q = 0; q < 8; q++) f[q] = fmaxf(fmaf(f[q], sc[cb + q], tb[cb + q]), 0.f);
  *(uint4*)(o + i) = pack8(f);
}

// ---------------- MFMA GEMM + fused BN column stats ----------------
template <int MODE>
__global__ __launch_bounds__(256) void k_gemm(const unsigned short* __restrict__ A,
                                              const unsigned short* __restrict__ Wt,
                                              unsigned short* __restrict__ out,
                                              const float* __restrict__ sc,
                                              const float* __restrict__ tb,
                                              float* __restrict__ ssum,
                                              float* __restrict__ ssq) {
  __shared__ unsigned short Zs[64 * 136];
  __shared__ float psum[16 * 128];
  __shared__ float psq[16 * 128];
  const int t = threadIdx.x;
  const int row0 = blockIdx.x * 64;

#pragma unroll
  for (int i = 0; i < 4; i++) {
    int q = t + i * 256;
    int r = q >> 4, cb = (q & 15) << 3;
    int grow = row0 + r;
    uint4 u = make_uint4(0u, 0u, 0u, 0u);
    if (grow < N_NODES) {
      u = *(const uint4*)(A + (size_t)grow * D + cb);
      if (MODE == 1) {
        float f[8];
        unpack8(u, f);
#pragma unroll
        for (int jj = 0; jj < 8; jj++)
          f[jj] = fmaxf(fmaf(f[jj], sc[cb + jj], tb[cb + jj]), 0.f);
        u = pack8(f);
      }
    }
    *(uint4*)&Zs[r * 136 + cb] = u;
  }
  __syncthreads();

  const int lane = t & 63;
  const int wave = t >> 6;
  const int quad = lane >> 4;
  const int lr = lane & 15;
  const int m0 = wave * 16;

  f32x4 acc[8];
#pragma unroll
  for (int i = 0; i < 8; i++) acc[i] = (f32x4){0.f, 0.f, 0.f, 0.f};

#pragma unroll
  for (int kc = 0; kc < 128; kc += 32) {
    short8 af = *(const short8*)&Zs[(m0 + lr) * 136 + kc + quad * 8];
#pragma unroll
    for (int nt = 0; nt < 8; nt++) {
      short8 bf = *(const short8*)(Wt + (size_t)(nt * 16 + lr) * D + kc + quad * 8);
      acc[nt] = __builtin_amdgcn_mfma_f32_16x16x32_bf16(af, bf, acc[nt], 0, 0, 0);
    }
  }

#pragma unroll
  for (int nt = 0; nt < 8; nt++) {
    int col = nt * 16 + lr;
    float s = acc[nt][0] + acc[nt][1] + acc[nt][2] + acc[nt][3];
    float qq = acc[nt][0] * acc[nt][0] + acc[nt][1] * acc[nt][1] +
               acc[nt][2] * acc[nt][2] + acc[nt][3] * acc[nt][3];
    int gi = (wave * 4 + quad) * 128 + col;
    psum[gi] = s;
    psq[gi] = qq;
  }

#pragma unroll
  for (int rr = 0; rr < 4; rr++) {
    int grow = row0 + m0 + quad * 4 + rr;
    if (grow < N_NODES) {
#pragma unroll
      for (int nt = 0; nt < 8; nt++)
        out[(size_t)grow * D + nt * 16 + lr] = f2bf(acc[nt][rr]);
    }
  }

  __syncthreads();
  if (t < 128) {
    float S = 0.f, Q = 0.f;
#pragma unroll
    for (int i = 0; i < 16; i++) {
      S += psum[i * 128 + t];
      Q += psq[i * 128 + t];
    }
    int slice = blockIdx.x & (NSLICE - 1);
    atomicAdd(&ssum[slice * 128 + t], S);
    atomicAdd(&ssq[slice * 128 + t], Q);
  }
}

// fold stats -> affine BN coeffs: bn(y) = y*sc + tb
__global__ void k_bnfin(const float* __restrict__ ssum, const float* __restrict__ ssq,
                        const float* __restrict__ gamma, const float* __restrict__ beta,
                        float* __restrict__ sc, float* __restrict__ tb) {
  int f = threadIdx.x;
  float S = 0.f, Q = 0.f;
  for (int i = 0; i < NSLICE; i++) { S += ssum[i * 128 + f]; Q += ssq[i * 128 + f]; }
  float m = S * (1.0f / (float)N_NODES);
  float v = Q * (1.0f / (float)N_NODES) - m * m;
  float r = rsqrtf(v + BN_EPS);
  float s = r * gamma[f];
  sc[f] = s;
  tb[f] = beta[f] - m * s;
}

// ---------------- fused BN2+ReLU + node_emb write + graph readout ------------
#define RCH 64
__global__ __launch_bounds__(128) void k_readout(const unsigned short* __restrict__ y,
                                                 const int* __restrict__ batch,
                                                 const float* __restrict__ sc,
                                                 const float* __restrict__ tb,
                                                 float* __restrict__ node_out,
                                                 float* __restrict__ gsum,
                                                 int* __restrict__ gcnt) {
  int start = blockIdx.x * RCH;
  int end = min(start + RCH, N_NODES);
  if (start >= end) return;
  int f = threadIdx.x;
  float s = sc[f], tt = tb[f];
  float acc = 0.f;
  int cnt = 0;
  int curg = batch[start];
  for (int n = start; n < end; n++) {
    int gg = batch[n];
    float v = fmaxf(fmaf(bf2f(y[(size_t)n * D + f]), s, tt), 0.f);
    node_out[(size_t)n * D + f] = v;
    if (gg != curg) {
      atomicAdd(&gsum[curg * D + f], acc);
      if (f == 0) atomicAdd(&gcnt[curg], cnt);
      acc = 0.f; cnt = 0; curg = gg;
    }
    acc += v;
    cnt++;
  }
  atomicAdd(&gsum[curg * D + f], acc);
  if (f == 0) atomicAdd(&gcnt[curg], cnt);
}

__global__ __launch_bounds__(128) void k_gnorm(const float* __restrict__ gsum,
                                               const int* __restrict__ gcnt,
                                               float* __restrict__ out) {
  __shared__ float red[128];
  int g = blockIdx.x, f = threadIdx.x;
  float c = (float)gcnt[g];
  float v = gsum[g * D + f] / fmaxf(c, 1.0f);
  red[f] = v * v;
  __syncthreads();
  for (int o = 64; o > 0; o >>= 1) {
    if (f < o) red[f] += red[f + o];
    __syncthreads();
  }
  float nrm = sqrtf(red[0]);
  out[(size_t)g * D + f] = v / fmaxf(nrm, 1e-12f);
}

extern "C" void kernel_launch(void* const* d_in, const int* in_sizes, int n_in,
                              void* d_out, int out_size, void* d_ws, size_t ws_size,
                              hipStream_t stream) {
  const float* x   = (const float*)d_in[0];
  const int*   ei  = (const int*)d_in[1];
  const int*   bat = (const int*)d_in[2];
  const float* W1  = (const float*)d_in[3];
  const float* g1  = (const float*)d_in[4];
  const float* b1  = (const float*)d_in[5];
  const float* W2  = (const float*)d_in[6];
  const float* g2  = (const float*)d_in[7];
  const float* b2  = (const float*)d_in[8];
  const float* eps = (const float*)d_in[9];
  float* out = (float*)d_out;

  char* w = (char*)d_ws;
  const size_t FEAT_B = (size_t)N_NODES * D * 2;
  // xb: layer-0 gather source; dead after layer-0 aggz, then reused as the
  // pre-materialized relu(bn(y2)) buffer for layers 1-2.
  unsigned short* xb   = (unsigned short*)w; w += FEAT_B;
  unsigned short* bufA = (unsigned short*)w; w += FEAT_B;
  unsigned short* bufB = (unsigned short*)w; w += FEAT_B;
  unsigned short* bufC = (unsigned short*)w; w += FEAT_B;
  unsigned short* WtB  = (unsigned short*)w; w += (size_t)6 * D * D * 2;
  int* off   = (int*)w; w += 400016;
  int* ebase = (int*)w; w += 2048;
  int* gcur  = (int*)w; w += 2048;
  int* esrc  = (int*)w; w += (size_t)N_EDGES * 4;
  float* sc1 = (float*)w; w += 512;
  float* tb1 = (float*)w; w += 512;
  float* sc2 = (float*)w; w += 512;
  float* tb2 = (float*)w; w += 512;
  // zero-init region (single memset): ecount | stats | gsum | gcnt
  char* zreg = w;
  int* ecount  = (int*)w; w += 2048;
  float* stats = (float*)w; w += (size_t)6 * 2 * NSLICE * 128 * 4;  // 96 KB
  float* gsum  = (float*)w; w += (size_t)N_GRAPHS * D * 4;
  int* gcnt    = (int*)w; w += 256;
  size_t zbytes = (size_t)((char*)w - zreg);
  // pairs (12.8 MB) aliases bufB — unused until first k_gemm, scatB done by then.
  int2* pairs = (int2*)bufB;

  hipMemsetAsync(zreg, 0, zbytes, stream);

  k_cast<<<(N_NODES * D / 8 + 255) / 256, 256, 0, stream>>>(x, xb);
  k_wprep<<<dim3(6, 128), 128, 0, stream>>>(W1, W2, WtB);

  k_histb<<<NABLK, 256, 0, stream>>>(ei + N_EDGES, ecount);
  k_scanb<<<1, 512, 0, stream>>>(ecount, ebase, gcur);
  k_scatA<<<NABLK, 256, 0, stream>>>(ei, gcur, pairs);
  k_scatB<<<NBUCK, 256, 0, stream>>>(pairs, ebase, off, esrc);

  const int gemm_grid = (N_NODES + 63) / 64;  // 1563
  const int aggz_grid = N_NODES / 4;          // 25000 exactly
  const int ew_grid = (N_NODES * D / 8 + 255) / 256;

  for (int l = 0; l < 3; l++) {
    float* s1 = stats + (size_t)(l * 2 + 0) * 2 * NSLICE * 128;
    float* q1 = s1 + NSLICE * 128;
    float* s2 = stats + (size_t)(l * 2 + 1) * 2 * NSLICE * 128;
    float* q2 = s2 + NSLICE * 128;
    if (l > 0) {
      // pre-materialize h = relu(bn2(y2)) once (cheaper than per-edge BN)
      k_ew<<<ew_grid, 256, 0, stream>>>(bufC, sc2, tb2, xb);
    }
    k_aggz<<<aggz_grid, 256, 0, stream>>>(xb, off, esrc, eps + l, bufA);
    k_gemm<0><<<gemm_grid, 256, 0, stream>>>(bufA, WtB + (size_t)(l * 2 + 0) * D * D, bufB,
                                             nullptr, nullptr, s1, q1);
    k_bnfin<<<1, 128, 0, stream>>>(s1, q1, g1 + (size_t)l * D, b1 + (size_t)l * D, sc1, tb1);
    k_gemm<1><<<gemm_grid, 256, 0, stream>>>(bufB, WtB + (size_t)(l * 2 + 1) * D * D, bufC,
                                             sc1, tb1, s2, q2);
    k_bnfin<<<1, 128, 0, stream>>>(s2, q2, g2 + (size_t)l * D, b2 + (size_t)l * D, sc2, tb2);
  }

  k_readout<<<(N_NODES + RCH - 1) / RCH, 128, 0, stream>>>(bufC, bat, sc2, tb2,
                                                           out, gsum, gcnt);
  k_gnorm<<<N_GRAPHS, 128, 0, stream>>>(gsum, gcnt, out + (size_t)N_NODES * D);
}